// Round 14
// baseline (257.063 us; speedup 1.0000x reference)
//
#include <hip/hip_runtime.h>
#include <math.h>
#include <stdint.h>

#define B_   2
#define TQ_  512
#define TK_  8192
#define D_   1024
#define NH_  16
#define HD_  64

#define NEG_BIG (-3.0e38f)
#define ASPLIT 8
#define LOG2E 1.4426950408889634f
#define EXP2F(x) __builtin_exp2f(x)

typedef __attribute__((ext_vector_type(8))) short short8;
typedef __attribute__((ext_vector_type(4))) float f32x4;

// ---------------- bf16 helpers (RNE) ----------------
__device__ __forceinline__ unsigned short f2bf(float x) {
    unsigned u = __float_as_uint(x);
    unsigned r = u + 0x7FFFu + ((u >> 16) & 1u);
    return (unsigned short)(r >> 16);
}
__device__ __forceinline__ float bf2f(unsigned short h) {
    return __uint_as_float(((unsigned)h) << 16);
}
__device__ __forceinline__ short8 pack_bf16x8(float4 lo, float4 hi) {
    union { short8 v; unsigned u[4]; } P;
    asm("v_cvt_pk_bf16_f32 %0, %1, %2" : "=v"(P.u[0]) : "v"(lo.x), "v"(lo.y));
    asm("v_cvt_pk_bf16_f32 %0, %1, %2" : "=v"(P.u[1]) : "v"(lo.z), "v"(lo.w));
    asm("v_cvt_pk_bf16_f32 %0, %1, %2" : "=v"(P.u[2]) : "v"(hi.x), "v"(hi.y));
    asm("v_cvt_pk_bf16_f32 %0, %1, %2" : "=v"(P.u[3]) : "v"(hi.z), "v"(hi.w));
    return P.v;
}

#define GLD16(gp, lp)                                                              \
    __builtin_amdgcn_global_load_lds(                                              \
        (const __attribute__((address_space(1))) unsigned int*)(gp),               \
        (__attribute__((address_space(3))) unsigned int*)(lp), 16, 0, 0)

// ---------------- fp32 -> bf16 conversion of 4 weight matrices in one launch ----------------
__global__ __launch_bounds__(256)
void split_w4(const float* __restrict__ W0, const float* __restrict__ W1,
              const float* __restrict__ W2, const float* __restrict__ W3,
              unsigned short* __restrict__ O0, unsigned short* __restrict__ O1,
              unsigned short* __restrict__ O2, unsigned short* __restrict__ O3)
{
    const float* W; unsigned short* O;
    switch (blockIdx.y) {
        case 0:  W = W0; O = O0; break;
        case 1:  W = W1; O = O1; break;
        case 2:  W = W2; O = O2; break;
        default: W = W3; O = O3; break;
    }
    size_t i = ((size_t)blockIdx.x * 256 + threadIdx.x) * 8;
    float4 x0 = *(const float4*)(W + i);
    float4 x1 = *(const float4*)(W + i + 4);
    float a[8] = {x0.x, x0.y, x0.z, x0.w, x1.x, x1.y, x1.z, x1.w};
    union { short8 v; unsigned short u[8]; } H;
#pragma unroll
    for (int j = 0; j < 8; ++j) H.u[j] = f2bf(a[j]);
    *(short8*)(O + i) = H.v;
}

// ---------------- fp32 -> bf16 conversion (generic) ----------------
__global__ __launch_bounds__(256)
void split_w(const float* __restrict__ W, unsigned short* __restrict__ Wh)
{
    size_t i = ((size_t)blockIdx.x * 256 + threadIdx.x) * 8;
    float4 x0 = *(const float4*)(W + i);
    float4 x1 = *(const float4*)(W + i + 4);
    float a[8] = {x0.x, x0.y, x0.z, x0.w, x1.x, x1.y, x1.z, x1.w};
    union { short8 v; unsigned short u[8]; } H;
#pragma unroll
    for (int j = 0; j < 8; ++j) H.u[j] = f2bf(a[j]);
    *(short8*)(Wh + i) = H.v;
}

// ---------------- bias @ W^T group vectors: gv[g][n] = sum_d bias_g[d]*W[n][d] ----------------
// (kv + bias_g) @ W^T == kv @ W^T + gv[g]  -- lets the kv GEMM read raw fp32 kv.
__global__ __launch_bounds__(256)
void bias_gemv(const float* __restrict__ Wk, const float* __restrict__ Wv,
               const float* __restrict__ ab, const float* __restrict__ ib,
               float* __restrict__ gvK, float* __restrict__ gvV)
{
    const int comb = blockIdx.y;            // 0:(Wk,ab) 1:(Wk,ib) 2:(Wv,ab) 3:(Wv,ib)
    const float* W = (comb < 2) ? Wk : Wv;
    const float* g = (comb & 1) ? ib : ab;
    float* out = ((comb < 2) ? gvK : gvV) + (comb & 1) * D_;
    const int n = blockIdx.x * 256 + threadIdx.x;
    const float* wr = W + (size_t)n * D_;
    float acc = 0.f;
    for (int d = 0; d < D_; d += 4) {
        float4 w4 = *(const float4*)(wr + d);
        float4 g4 = *(const float4*)(g + d);
        acc += w4.x * g4.x + w4.y * g4.y + w4.z * g4.z + w4.w * g4.w;
    }
    out[n] = acc;
}

// ---------------- Q projection, bf16 MFMA; scale folds 1/(64*temp) AND log2e ----------------
__global__ __launch_bounds__(256)
void sdpca_gemm_q(const unsigned short* __restrict__ A, const unsigned short* __restrict__ W,
                  const float* __restrict__ bias, const float* __restrict__ log_temp,
                  unsigned short* __restrict__ Qb)
{
    __shared__ unsigned short AT[128 * 32];
    __shared__ unsigned short BT[128 * 32];
    const int tid  = threadIdx.x;
    const int lane = tid & 63;
    const int w    = tid >> 6;
    const int brow = blockIdx.y * 128;
    const int bcol = blockIdx.x * 128;
    const int wr = w >> 1, wc = w & 1;

    const int   srow = lane >> 2;
    const int   scol = (((lane & 3) ^ ((lane >> 3) & 3)) * 8);
    const size_t gA0 = (size_t)(brow + w * 32 + srow) * D_ + scol;
    const size_t gA1 = gA0 + (size_t)16 * D_;
    const size_t gB0 = (size_t)(bcol + w * 32 + srow) * D_ + scol;
    const size_t gB1 = gB0 + (size_t)16 * D_;
    const int   l0   = (w * 32 +  0) * 32;
    const int   l1   = (w * 32 + 16) * 32;

    f32x4 acc[4][4];
#pragma unroll
    for (int m = 0; m < 4; ++m)
#pragma unroll
        for (int n = 0; n < 4; ++n) acc[m][n] = (f32x4){0.f, 0.f, 0.f, 0.f};

    const int frow = lane & 15;
    const int fko  = (((lane >> 4) ^ ((frow >> 1) & 3)) * 8);

    for (int k0 = 0; k0 < D_; k0 += 32) {
        GLD16(A + gA0 + k0, &AT[l0]);
        GLD16(A + gA1 + k0, &AT[l1]);
        GLD16(W + gB0 + k0, &BT[l0]);
        GLD16(W + gB1 + k0, &BT[l1]);
        __syncthreads();
        short8 bf[4];
#pragma unroll
        for (int n = 0; n < 4; ++n)
            bf[n] = *(const short8*)&BT[(wc * 64 + n * 16 + frow) * 32 + fko];
#pragma unroll
        for (int m = 0; m < 4; ++m) {
            short8 a = *(const short8*)&AT[(wr * 64 + m * 16 + frow) * 32 + fko];
#pragma unroll
            for (int n = 0; n < 4; ++n)
                acc[m][n] = __builtin_amdgcn_mfma_f32_16x16x32_bf16(a, bf[n], acc[m][n], 0, 0, 0);
        }
        __syncthreads();
    }

    float lt    = *log_temp;
    float temp  = fminf(fmaxf(expf(lt), 0.1f), 10.0f);
    float scale = LOG2E / (64.0f * temp);

#pragma unroll
    for (int n = 0; n < 4; ++n) {
        int col = bcol + wc * 64 + n * 16 + frow;
        float bsv = bias[col];
#pragma unroll
        for (int m = 0; m < 4; ++m) {
            int rbase = brow + wr * 64 + m * 16 + (lane >> 4) * 4;
#pragma unroll
            for (int r = 0; r < 4; ++r)
                Qb[(size_t)(rbase + r) * D_ + col] = f2bf((acc[m][n][r] + bsv) * scale);
        }
    }
}

// ---------------- fused K/V projection: fp32 kv in, bias via gv vectors ----------------
// Reg-staged A (fp32 -> cvt_pk bf16 in flight) and B, t+1 prefetch under compute;
// barriers drain lgkm only (no global_load_lds). Same XOR chunk swizzle:
// write LDS chunk cg^s(r) with global chunk cg  =>  LDS[r][c'] = global[r][c'^s(r)].
__global__ __launch_bounds__(256)
void sdpca_gemm_kv_fused(const float* __restrict__ kv,
                         const unsigned short* __restrict__ Whk,
                         const unsigned short* __restrict__ Whv,
                         const float* __restrict__ bk, const float* __restrict__ bv,
                         const float* __restrict__ gvK, const float* __restrict__ gvV,
                         const int* __restrict__ nactp,
                         unsigned short* __restrict__ Kb, unsigned short* __restrict__ Vt)
{
    __shared__ unsigned short AT[128 * 32];
    __shared__ unsigned short BT[128 * 32];

    const int tid  = threadIdx.x;
    const int lane = tid & 63;
    const int w    = tid >> 6;
    const int bid  = blockIdx.x;
    const int lid  = (bid & 7) * 128 + (bid >> 3);
    const int brow = (lid >> 3) * 128;
    const int bcol = (lid & 7) * 128;
    const int z    = blockIdx.y;
    const int Na   = *nactp;

    const unsigned short* Wh = z ? Whv : Whk;
    const float* bias        = z ? bv  : bk;
    const float* gv          = z ? gvV : gvK;

    const int wr = w >> 1, wc = w & 1;

    const int srow = lane >> 2;                     // 0..15
    const int cg   = lane & 3;                      // natural 16B chunk
    const int cs   = cg ^ ((srow >> 1) & 3);        // swizzled LDS chunk
    const size_t gA0 = (size_t)(brow + w * 32 + srow) * D_ + cg * 8;   // fp32 elems
    const size_t gA1 = gA0 + (size_t)16 * D_;
    const size_t gB0 = (size_t)(bcol + w * 32 + srow) * D_ + cg * 8;   // bf16 elems
    const size_t gB1 = gB0 + (size_t)16 * D_;
    const int    la0 = (w * 32 + srow) * 32 + cs * 8;
    const int    la1 = (w * 32 + 16 + srow) * 32 + cs * 8;

    f32x4 acc[4][4];
#pragma unroll
    for (int m = 0; m < 4; ++m)
#pragma unroll
        for (int n = 0; n < 4; ++n) acc[m][n] = (f32x4){0.f, 0.f, 0.f, 0.f};

    const int frow = lane & 15;
    const int fko  = (((lane >> 4) ^ ((frow >> 1) & 3)) * 8);

    // prefetch tile 0
    float4 a00 = *(const float4*)(kv + gA0);
    float4 a01 = *(const float4*)(kv + gA0 + 4);
    float4 a10 = *(const float4*)(kv + gA1);
    float4 a11 = *(const float4*)(kv + gA1 + 4);
    short8 br0 = *(const short8*)(Wh + gB0);
    short8 br1 = *(const short8*)(Wh + gB1);

    for (int k0 = 0; k0 < D_; k0 += 32) {
        __syncthreads();                     // previous tile fully consumed
        *(short8*)&AT[la0] = pack_bf16x8(a00, a01);
        *(short8*)&AT[la1] = pack_bf16x8(a10, a11);
        *(short8*)&BT[la0] = br0;
        *(short8*)&BT[la1] = br1;
        __syncthreads();                     // tile staged (lgkm drain only)

        if (k0 + 32 < D_) {                  // prefetch t+1, hides under compute
            a00 = *(const float4*)(kv + gA0 + k0 + 36 - 4);
            a01 = *(const float4*)(kv + gA0 + k0 + 36);
            a10 = *(const float4*)(kv + gA1 + k0 + 32);
            a11 = *(const float4*)(kv + gA1 + k0 + 36);
            br0 = *(const short8*)(Wh + gB0 + k0 + 32);
            br1 = *(const short8*)(Wh + gB1 + k0 + 32);
        }

        short8 bf[4];
#pragma unroll
        for (int n = 0; n < 4; ++n)
            bf[n] = *(const short8*)&BT[(wc * 64 + n * 16 + frow) * 32 + fko];
#pragma unroll
        for (int m = 0; m < 4; ++m) {
            short8 a = *(const short8*)&AT[(wr * 64 + m * 16 + frow) * 32 + fko];
#pragma unroll
            for (int n = 0; n < 4; ++n)
                acc[m][n] = __builtin_amdgcn_mfma_f32_16x16x32_bf16(a, bf[n], acc[m][n], 0, 0, 0);
        }
    }

    if (z == 0) {
#pragma unroll
        for (int n = 0; n < 4; ++n) {
            int col = bcol + wc * 64 + n * 16 + frow;
            float bsv = bias[col];
            float g0  = gv[col], g1 = gv[D_ + col];
#pragma unroll
            for (int m = 0; m < 4; ++m) {
                int rbase = brow + wr * 64 + m * 16 + (lane >> 4) * 4;
#pragma unroll
                for (int r = 0; r < 4; ++r) {
                    int tok = (rbase + r) & (TK_ - 1);
                    float gval = (tok < Na) ? g0 : g1;
                    Kb[(size_t)(rbase + r) * D_ + col] = f2bf(acc[m][n][r] + bsv + gval);
                }
            }
        }
    } else {
#pragma unroll
        for (int n = 0; n < 4; ++n) {
            int col = bcol + wc * 64 + n * 16 + frow;
            int h   = col >> 6, d = col & 63;
            float bsv = bias[col];
            float g0  = gv[col], g1 = gv[D_ + col];
#pragma unroll
            for (int m = 0; m < 4; ++m) {
                int rbase = brow + wr * 64 + m * 16 + (lane >> 4) * 4;
                int b     = rbase >> 13;
                int tok   = rbase & (TK_ - 1);
                ushort4 o;
                o.x = f2bf(acc[m][n][0] + bsv + ((tok + 0 < Na) ? g0 : g1));
                o.y = f2bf(acc[m][n][1] + bsv + ((tok + 1 < Na) ? g0 : g1));
                o.z = f2bf(acc[m][n][2] + bsv + ((tok + 2 < Na) ? g0 : g1));
                o.w = f2bf(acc[m][n][3] + bsv + ((tok + 3 < Na) ? g0 : g1));
                *(ushort4*)&Vt[((size_t)(b * 16 + h) * 64 + d) * TK_ + tok] = o;
            }
        }
    }
}

// ---------------- MFMA flash attention, fixed-max (m=0) softmax, setprio on MFMA ----------------
template<bool FULL>
__device__ __forceinline__ void attn_pass(
    const f32x4 st[4], int jb, int lo, int hi,
    f32x4& lacc, f32x4 o[4],
    unsigned short* Ps, const unsigned short* Vs,
    int frow, int g, int w)
{
    const int q = w * 16 + frow;
    const short8 kOnes = {(short)0x3F80, (short)0x3F80, (short)0x3F80, (short)0x3F80,
                          (short)0x3F80, (short)0x3F80, (short)0x3F80, (short)0x3F80};
    float p[4][4];
#pragma unroll
    for (int mt = 0; mt < 4; ++mt)
#pragma unroll
        for (int r = 0; r < 4; ++r) {
            float pv = EXP2F(st[mt][r]);
            if (!FULL) {
                int key = jb + mt * 16 + g * 4 + r;
                if (key < lo || key >= hi) pv = 0.f;
            }
            p[mt][r] = pv;
        }

#pragma unroll
    for (int mt = 0; mt < 4; ++mt) {
        unsigned u0, u1;
        asm("v_cvt_pk_bf16_f32 %0, %1, %2" : "=v"(u0) : "v"(p[mt][0]), "v"(p[mt][1]));
        asm("v_cvt_pk_bf16_f32 %0, %1, %2" : "=v"(u1) : "v"(p[mt][2]), "v"(p[mt][3]));
        unsigned* dst = (unsigned*)((char*)Ps + q * 144 + (mt * 16 + g * 4) * 2);
        dst[0] = u0; dst[1] = u1;
    }
    __builtin_amdgcn_sched_barrier(0);   // keep PV reads after P writes

    short8 pb[2];
#pragma unroll
    for (int ks = 0; ks < 2; ++ks)
        pb[ks] = *(const short8*)((const char*)Ps + q * 144 + ks * 64 + g * 16);
    __builtin_amdgcn_s_setprio(1);
#pragma unroll
    for (int mt = 0; mt < 4; ++mt) {
        int row = mt * 16 + frow;
        int rs  = (row & 7) << 4;
#pragma unroll
        for (int ks = 0; ks < 2; ++ks) {
            short8 a = *(const short8*)((const char*)Vs + row * 128 + ((ks * 64 + g * 16) ^ rs));
            o[mt] = __builtin_amdgcn_mfma_f32_16x16x32_bf16(a, pb[ks], o[mt], 0, 0, 0);
        }
    }
#pragma unroll
    for (int ks = 0; ks < 2; ++ks)
        lacc = __builtin_amdgcn_mfma_f32_16x16x32_bf16(kOnes, pb[ks], lacc, 0, 0, 0);
    __builtin_amdgcn_s_setprio(0);
}

__global__ __launch_bounds__(256)
void sdpca_attn_mfma(const unsigned short* __restrict__ Qb,
                     const unsigned short* __restrict__ Kb,
                     const unsigned short* __restrict__ Vt,
                     const int* __restrict__ nactp,
                     unsigned short* __restrict__ pO, float* __restrict__ pL)
{
    __shared__ char smem[25600];
    unsigned short* Ks = (unsigned short*)smem;
    unsigned short* Vs = (unsigned short*)(smem + 8192);
    unsigned short* Ps = (unsigned short*)(smem + 16384);
    float*          Ot = (float*)smem;

    const int tid  = threadIdx.x;
    const int l    = tid & 63, w = tid >> 6;
    const int frow = l & 15,  g = l >> 4;

    const int bid = blockIdx.x;
    const int lid = (bid & 7) * 256 + (bid >> 3);
    const int q0  = (lid & 7) * 64;
    const int bh  = (lid >> 3) & 31;
    const int s   = lid >> 8;
    const int b   = bh >> 4, h = bh & 15;

    const int Na   = *nactp;
    const int ks0  = s * (TK_ / ASPLIT);
    const int nt   = TK_ / ASPLIT / 64;

    short8 qf0, qf1;
    {
        const unsigned short* qp = Qb + (size_t)(b * TQ_ + q0 + w * 16 + frow) * D_ + h * HD_;
        qf0 = *(const short8*)(qp + g * 8);
        qf1 = *(const short8*)(qp + 32 + g * 8);
    }

    f32x4 lA4 = (f32x4){0.f, 0.f, 0.f, 0.f};
    f32x4 lI4 = (f32x4){0.f, 0.f, 0.f, 0.f};
    f32x4 oA[4], oI[4];
#pragma unroll
    for (int mt = 0; mt < 4; ++mt) {
        oA[mt] = (f32x4){0.f, 0.f, 0.f, 0.f};
        oI[mt] = (f32x4){0.f, 0.f, 0.f, 0.f};
    }

    const int srow = tid >> 2;
    const int scb  = (tid & 3) * 32;
    const unsigned short* kg = Kb + (size_t)(b * TK_ + ks0 + srow) * D_ + h * HD_ + (tid & 3) * 16;
    const unsigned short* vg = Vt + ((size_t)bh * HD_ + srow) * TK_ + ks0 + (tid & 3) * 16;
    const int kswz0 = srow * 128 + ((scb +  0) ^ ((srow & 7) << 4));
    const int kswz1 = srow * 128 + ((scb + 16) ^ ((srow & 7) << 4));

    // prefetch tile 0
    short8 kr0 = *(const short8*)(kg);
    short8 kr1 = *(const short8*)(kg + 8);
    short8 vr0 = *(const short8*)(vg);
    short8 vr1 = *(const short8*)(vg + 8);
    kg += (size_t)64 * D_;
    vg += 64;

    for (int t = 0; t < nt; ++t) {
        const int jb = ks0 + t * 64;
        __syncthreads();
        *(short8*)((char*)Ks + kswz0) = kr0;
        *(short8*)((char*)Ks + kswz1) = kr1;
        *(short8*)((char*)Vs + kswz0) = vr0;
        *(short8*)((char*)Vs + kswz1) = vr1;
        __syncthreads();

        if (t + 1 < nt) {
            kr0 = *(const short8*)(kg);
            kr1 = *(const short8*)(kg + 8);
            vr0 = *(const short8*)(vg);
            vr1 = *(const short8*)(vg + 8);
            kg += (size_t)64 * D_;
            vg += 64;
        }

        f32x4 st[4];
        __builtin_amdgcn_s_setprio(1);
#pragma unroll
        for (int mt = 0; mt < 4; ++mt) {
            int row = mt * 16 + frow;
            int rs  = (row & 7) << 4;
            short8 a0 = *(const short8*)((const char*)Ks + row * 128 + ((g * 16) ^ rs));
            short8 a1 = *(const short8*)((const char*)Ks + row * 128 + ((64 + g * 16) ^ rs));
            f32x4 acc = (f32x4){0.f, 0.f, 0.f, 0.f};
            acc = __builtin_amdgcn_mfma_f32_16x16x32_bf16(a0, qf0, acc, 0, 0, 0);
            acc = __builtin_amdgcn_mfma_f32_16x16x32_bf16(a1, qf1, acc, 0, 0, 0);
            st[mt] = acc;
        }
        __builtin_amdgcn_s_setprio(0);

        const bool hasA = (jb < Na);
        const bool hasI = (jb + 64 > Na);
        if (hasA) {
            if (jb + 64 <= Na) attn_pass<true >(st, jb, 0, Na, lA4, oA, Ps, Vs, frow, g, w);
            else               attn_pass<false>(st, jb, 0, Na, lA4, oA, Ps, Vs, frow, g, w);
        }
        if (hasI) {
            if (jb >= Na)      attn_pass<true >(st, jb, Na, TK_, lI4, oI, Ps, Vs, frow, g, w);
            else               attn_pass<false>(st, jb, Na, TK_, lI4, oI, Ps, Vs, frow, g, w);
        }
    }

    const int q = w * 16 + frow;
#pragma unroll
    for (int grp = 0; grp < 2; ++grp) {
        __syncthreads();
        const f32x4* o = grp ? oI : oA;
#pragma unroll
        for (int mt = 0; mt < 4; ++mt)
            *(f32x4*)&Ot[q * 68 + mt * 16 + g * 4] = o[mt];
        if (g == 0) {
            size_t base = ((size_t)((s * 2 + grp) * (B_ * NH_) + bh)) * TQ_ + q0 + q;
            pL[base] = grp ? lI4[0] : lA4[0];
        }
        __syncthreads();
        {
            int qr = tid >> 2, dc = (tid & 3) * 16;
            size_t rowbase = ((size_t)((s * 2 + grp) * (B_ * NH_) + bh)) * TQ_ + q0 + qr;
            unsigned short* dst = pO + rowbase * HD_ + dc;
            union { short8 v; unsigned short u[8]; } o0, o1;
#pragma unroll
            for (int j = 0; j < 8; ++j) {
                o0.u[j] = f2bf(Ot[qr * 68 + dc + j]);
                o1.u[j] = f2bf(Ot[qr * 68 + dc + 8 + j]);
            }
            *(short8*)(dst)     = o0.v;
            *(short8*)(dst + 8) = o1.v;
        }
    }
}

// ---------------- split-K merge: plain sums (shared m=0), bf16 pO in, bf16 out ----------------
__global__ __launch_bounds__(256)
void sdpca_combine(const unsigned short* __restrict__ pO, const float* __restrict__ pL,
                   const int* __restrict__ nactp, unsigned short* __restrict__ Aob)
{
    int idx = blockIdx.x * 256 + threadIdx.x;
    int d   = idx & (HD_ - 1);
    int q   = (idx >> 6) & (TQ_ - 1);
    int bh  = idx >> 15;
    int b   = bh >> 4, h = bh & 15;
    int Na  = *nactp;
    int Ni  = TK_ - Na;

    float res = 0.f;
#pragma unroll
    for (int gg = 0; gg < 2; ++gg) {
        float L = 0.f, O = 0.f;
#pragma unroll
        for (int ss = 0; ss < ASPLIT; ++ss) {
            size_t ii = ((size_t)((ss * 2 + gg) * (B_ * NH_) + bh)) * TQ_ + q;
            L += pL[ii];
            O += bf2f(pO[ii * HD_ + d]);
        }
        float r   = (L > 0.f) ? (O / L) : 0.f;
        int   cnt = (gg == 0) ? Na : Ni;
        float sc  = (cnt > 0) ? rsqrtf((float)cnt) : 0.f;
        res += (gg == 0) ? (sc * r) : (-sc * r);
    }
    Aob[((size_t)(b * TQ_ + q)) * D_ + h * HD_ + d] = f2bf(res);
}

// ---------------- output projection, bf16 MFMA, fp32 out ----------------
__global__ __launch_bounds__(256)
void sdpca_gemm_o(const unsigned short* __restrict__ A, const unsigned short* __restrict__ W,
                  const float* __restrict__ bias, float* __restrict__ C)
{
    __shared__ unsigned short AT[128 * 32];
    __shared__ unsigned short BT[128 * 32];
    const int tid  = threadIdx.x;
    const int lane = tid & 63;
    const int w    = tid >> 6;
    const int brow = blockIdx.y * 128;
    const int bcol = blockIdx.x * 128;
    const int wr = w >> 1, wc = w & 1;

    const int   srow = lane >> 2;
    const int   scol = (((lane & 3) ^ ((lane >> 3) & 3)) * 8);
    const size_t gA0 = (size_t)(brow + w * 32 + srow) * D_ + scol;
    const size_t gA1 = gA0 + (size_t)16 * D_;
    const size_t gB0 = (size_t)(bcol + w * 32 + srow) * D_ + scol;
    const size_t gB1 = gB0 + (size_t)16 * D_;
    const int   l0   = (w * 32 +  0) * 32;
    const int   l1   = (w * 32 + 16) * 32;

    f32x4 acc[4][4];
#pragma unroll
    for (int m = 0; m < 4; ++m)
#pragma unroll
        for (int n = 0; n < 4; ++n) acc[m][n] = (f32x4){0.f, 0.f, 0.f, 0.f};

    const int frow = lane & 15;
    const int fko  = (((lane >> 4) ^ ((frow >> 1) & 3)) * 8);

    for (int k0 = 0; k0 < D_; k0 += 32) {
        GLD16(A + gA0 + k0, &AT[l0]);
        GLD16(A + gA1 + k0, &AT[l1]);
        GLD16(W + gB0 + k0, &BT[l0]);
        GLD16(W + gB1 + k0, &BT[l1]);
        __syncthreads();
        short8 bf[4];
#pragma unroll
        for (int n = 0; n < 4; ++n)
            bf[n] = *(const short8*)&BT[(wc * 64 + n * 16 + frow) * 32 + fko];
#pragma unroll
        for (int m = 0; m < 4; ++m) {
            short8 a = *(const short8*)&AT[(wr * 64 + m * 16 + frow) * 32 + fko];
#pragma unroll
            for (int n = 0; n < 4; ++n)
                acc[m][n] = __builtin_amdgcn_mfma_f32_16x16x32_bf16(a, bf[n], acc[m][n], 0, 0, 0);
        }
        __syncthreads();
    }

#pragma unroll
    for (int n = 0; n < 4; ++n) {
        int col = bcol + wc * 64 + n * 16 + frow;
        float bsv = bias[col];
#pragma unroll
        for (int m = 0; m < 4; ++m) {
            int rbase = brow + wr * 64 + m * 16 + (lane >> 4) * 4;
#pragma unroll
            for (int r = 0; r < 4; ++r)
                C[(size_t)(rbase + r) * D_ + col] = acc[m][n][r] + bsv;
        }
    }
}

extern "C" void kernel_launch(void* const* d_in, const int* in_sizes, int n_in,
                              void* d_out, int out_size, void* d_ws, size_t ws_size,
                              hipStream_t stream) {
    (void)in_sizes; (void)n_in; (void)out_size; (void)ws_size;
    const float* q   = (const float*)d_in[0];
    const float* kv  = (const float*)d_in[1];
    const float* Wq  = (const float*)d_in[2];
    const float* bq  = (const float*)d_in[3];
    const float* Wk  = (const float*)d_in[4];
    const float* bk  = (const float*)d_in[5];
    const float* Wv  = (const float*)d_in[6];
    const float* bv  = (const float*)d_in[7];
    const float* Wo  = (const float*)d_in[8];
    const float* bo  = (const float*)d_in[9];
    const float* ab  = (const float*)d_in[10];
    const float* ib  = (const float*)d_in[11];
    const float* lt  = (const float*)d_in[12];
    const int*   na  = (const int*)d_in[13];

    char* ws = (char*)d_ws;
    const size_t nQ  = (size_t)B_ * TQ_ * D_;    // 1,048,576
    const size_t nKV = (size_t)B_ * TK_ * D_;    // 16,777,216
    const size_t nW  = (size_t)D_ * D_;          // 1,048,576
    const size_t nML = (size_t)ASPLIT * 2 * B_ * NH_ * TQ_;  // 262,144

    float*          gvK = (float*)ws;                          // 8 KB (2 x 1024)
    float*          gvV = gvK + 2 * D_;                        // 8 KB
    unsigned short* Whk = (unsigned short*)(gvV + 2 * D_);     // 2 MB
    unsigned short* Whv = Whk + nW;                            // 2 MB
    unsigned short* Kb  = Whv + nW;                            // 33.5 MB
    unsigned short* Vt  = Kb + nKV;                            // 33.5 MB
    unsigned short* Qb  = Vt + nKV;                            // 2 MB
    unsigned short* qbb = Qb + nQ;                             // 2 MB
    unsigned short* Wqb = qbb + nQ;                            // 2 MB
    unsigned short* Wob = Wqb + nW;                            // 2 MB
    unsigned short* Aob = Wob + nW;                            // 2 MB
    float* pL = (float*)(Aob + nQ);                            // 1 MB
    unsigned short* pO = (unsigned short*)(pL + nML);          // 33.5 MB
    // total ~113 MB

    dim3 blk(256);
    split_w            <<<dim3((int)(nQ / 8 / 256)),  blk, 0, stream>>>(q,  qbb);
    split_w4           <<<dim3((int)(nW / 8 / 256), 4), blk, 0, stream>>>(
        Wq, Wo, Wk, Wv, Wqb, Wob, Whk, Whv);
    bias_gemv          <<<dim3(4, 4),                 blk, 0, stream>>>(Wk, Wv, ab, ib, gvK, gvV);
    sdpca_gemm_q       <<<dim3(8, 8),                 blk, 0, stream>>>(qbb, Wqb, bq, lt, Qb);
    sdpca_gemm_kv_fused<<<dim3(1024, 2),              blk, 0, stream>>>(
        kv, Whk, Whv, bk, bv, gvK, gvV, na, Kb, Vt);
    sdpca_attn_mfma    <<<dim3(2048),                 blk, 0, stream>>>(Qb, Kb, Vt, na, pO, pL);
    sdpca_combine      <<<dim3((B_ * TQ_ * D_) / 256), blk, 0, stream>>>(pO, pL, na, Aob);
    sdpca_gemm_o       <<<dim3(8, 8),                 blk, 0, stream>>>(Aob, Wob, bo, (float*)d_out);
}

// Round 15
// 229.074 us; speedup vs baseline: 1.1222x; 1.1222x over previous
//
#include <hip/hip_runtime.h>
#include <math.h>
#include <stdint.h>

#define B_   2
#define TQ_  512
#define TK_  8192
#define D_   1024
#define NH_  16
#define HD_  64

#define NEG_BIG (-3.0e38f)
#define ASPLIT 8
#define LOG2E 1.4426950408889634f
#define EXP2F(x) __builtin_exp2f(x)

typedef __attribute__((ext_vector_type(8))) short short8;
typedef __attribute__((ext_vector_type(4))) float f32x4;

// ---------------- bf16 helpers (RNE) ----------------
__device__ __forceinline__ unsigned short f2bf(float x) {
    unsigned u = __float_as_uint(x);
    unsigned r = u + 0x7FFFu + ((u >> 16) & 1u);
    return (unsigned short)(r >> 16);
}
__device__ __forceinline__ float bf2f(unsigned short h) {
    return __uint_as_float(((unsigned)h) << 16);
}

#define GLD16(gp, lp)                                                              \
    __builtin_amdgcn_global_load_lds(                                              \
        (const __attribute__((address_space(1))) unsigned int*)(gp),               \
        (__attribute__((address_space(3))) unsigned int*)(lp), 16, 0, 0)

// ---------------- fp32 -> bf16 conversion of 5 equal-size (1M elem) tensors ----------------
__global__ __launch_bounds__(256)
void split_w5(const float* __restrict__ W0, const float* __restrict__ W1,
              const float* __restrict__ W2, const float* __restrict__ W3,
              const float* __restrict__ W4,
              unsigned short* __restrict__ O0, unsigned short* __restrict__ O1,
              unsigned short* __restrict__ O2, unsigned short* __restrict__ O3,
              unsigned short* __restrict__ O4)
{
    const float* W; unsigned short* O;
    switch (blockIdx.y) {
        case 0:  W = W0; O = O0; break;
        case 1:  W = W1; O = O1; break;
        case 2:  W = W2; O = O2; break;
        case 3:  W = W3; O = O3; break;
        default: W = W4; O = O4; break;
    }
    size_t i = ((size_t)blockIdx.x * 256 + threadIdx.x) * 8;
    float4 x0 = *(const float4*)(W + i);
    float4 x1 = *(const float4*)(W + i + 4);
    float a[8] = {x0.x, x0.y, x0.z, x0.w, x1.x, x1.y, x1.z, x1.w};
    union { short8 v; unsigned short u[8]; } H;
#pragma unroll
    for (int j = 0; j < 8; ++j) H.u[j] = f2bf(a[j]);
    *(short8*)(O + i) = H.v;
}

// ---------------- bf16 conversion of (kv + group bias) ----------------
__global__ __launch_bounds__(256)
void split_kv(const float* __restrict__ kv, const float* __restrict__ ab,
              const float* __restrict__ ib, const int* __restrict__ nactp,
              unsigned short* __restrict__ Ah)
{
    const int Na = *nactp;
    size_t i = ((size_t)blockIdx.x * 256 + threadIdx.x) * 8;
    int row = (int)(i >> 10);
    int col = (int)(i & (D_ - 1));
    const float* bp = ((row & (TK_ - 1)) < Na) ? ab : ib;
    float4 x0 = *(const float4*)(kv + i);
    float4 x1 = *(const float4*)(kv + i + 4);
    float4 b0 = *(const float4*)(bp + col);
    float4 b1 = *(const float4*)(bp + col + 4);
    float a[8] = {x0.x + b0.x, x0.y + b0.y, x0.z + b0.z, x0.w + b0.w,
                  x1.x + b1.x, x1.y + b1.y, x1.z + b1.z, x1.w + b1.w};
    union { short8 v; unsigned short u[8]; } H;
#pragma unroll
    for (int j = 0; j < 8; ++j) H.u[j] = f2bf(a[j]);
    *(short8*)(Ah + i) = H.v;
}

// ---------------- Q projection, bf16 MFMA; scale folds 1/(64*temp) AND log2e ----------------
__global__ __launch_bounds__(256)
void sdpca_gemm_q(const unsigned short* __restrict__ A, const unsigned short* __restrict__ W,
                  const float* __restrict__ bias, const float* __restrict__ log_temp,
                  unsigned short* __restrict__ Qb)
{
    __shared__ unsigned short AT[128 * 32];
    __shared__ unsigned short BT[128 * 32];
    const int tid  = threadIdx.x;
    const int lane = tid & 63;
    const int w    = tid >> 6;
    const int brow = blockIdx.y * 128;
    const int bcol = blockIdx.x * 128;
    const int wr = w >> 1, wc = w & 1;

    const int   srow = lane >> 2;
    const int   scol = (((lane & 3) ^ ((lane >> 3) & 3)) * 8);
    const size_t gA0 = (size_t)(brow + w * 32 + srow) * D_ + scol;
    const size_t gA1 = gA0 + (size_t)16 * D_;
    const size_t gB0 = (size_t)(bcol + w * 32 + srow) * D_ + scol;
    const size_t gB1 = gB0 + (size_t)16 * D_;
    const int   l0   = (w * 32 +  0) * 32;
    const int   l1   = (w * 32 + 16) * 32;

    f32x4 acc[4][4];
#pragma unroll
    for (int m = 0; m < 4; ++m)
#pragma unroll
        for (int n = 0; n < 4; ++n) acc[m][n] = (f32x4){0.f, 0.f, 0.f, 0.f};

    const int frow = lane & 15;
    const int fko  = (((lane >> 4) ^ ((frow >> 1) & 3)) * 8);

    for (int k0 = 0; k0 < D_; k0 += 32) {
        GLD16(A + gA0 + k0, &AT[l0]);
        GLD16(A + gA1 + k0, &AT[l1]);
        GLD16(W + gB0 + k0, &BT[l0]);
        GLD16(W + gB1 + k0, &BT[l1]);
        __syncthreads();
        short8 bf[4];
#pragma unroll
        for (int n = 0; n < 4; ++n)
            bf[n] = *(const short8*)&BT[(wc * 64 + n * 16 + frow) * 32 + fko];
#pragma unroll
        for (int m = 0; m < 4; ++m) {
            short8 a = *(const short8*)&AT[(wr * 64 + m * 16 + frow) * 32 + fko];
#pragma unroll
            for (int n = 0; n < 4; ++n)
                acc[m][n] = __builtin_amdgcn_mfma_f32_16x16x32_bf16(a, bf[n], acc[m][n], 0, 0, 0);
        }
        __syncthreads();
    }

    float lt    = *log_temp;
    float temp  = fminf(fmaxf(expf(lt), 0.1f), 10.0f);
    float scale = LOG2E / (64.0f * temp);

#pragma unroll
    for (int n = 0; n < 4; ++n) {
        int col = bcol + wc * 64 + n * 16 + frow;
        float bsv = bias[col];
#pragma unroll
        for (int m = 0; m < 4; ++m) {
            int rbase = brow + wr * 64 + m * 16 + (lane >> 4) * 4;
#pragma unroll
            for (int r = 0; r < 4; ++r)
                Qb[(size_t)(rbase + r) * D_ + col] = f2bf((acc[m][n][r] + bsv) * scale);
        }
    }
}

// ---------------- K/V projection via bf16 MFMA (BK=32), z picks K or V ----------------
__global__ __launch_bounds__(256)
void sdpca_gemm_kv_mfma(const unsigned short* __restrict__ Ah,
                        const unsigned short* __restrict__ Whk,
                        const unsigned short* __restrict__ Whv,
                        const float* __restrict__ bk, const float* __restrict__ bv,
                        unsigned short* __restrict__ Kb, unsigned short* __restrict__ Vt)
{
    __shared__ unsigned short AT[128 * 32];
    __shared__ unsigned short BT[128 * 32];

    const int tid  = threadIdx.x;
    const int lane = tid & 63;
    const int w    = tid >> 6;
    const int bid  = blockIdx.x;
    const int lid  = (bid & 7) * 128 + (bid >> 3);
    const int brow = (lid >> 3) * 128;
    const int bcol = (lid & 7) * 128;
    const int z    = blockIdx.y;

    const unsigned short* Wh = z ? Whv : Whk;
    const float* bias        = z ? bv  : bk;

    const int wr = w >> 1, wc = w & 1;

    const int   srow = lane >> 2;
    const int   scol = (((lane & 3) ^ ((lane >> 3) & 3)) * 8);
    const size_t gA0 = (size_t)(brow + w * 32 + srow) * D_ + scol;
    const size_t gA1 = gA0 + (size_t)16 * D_;
    const size_t gB0 = (size_t)(bcol + w * 32 + srow) * D_ + scol;
    const size_t gB1 = gB0 + (size_t)16 * D_;
    const int   l0   = (w * 32 +  0) * 32;
    const int   l1   = (w * 32 + 16) * 32;

    f32x4 acc[4][4];
#pragma unroll
    for (int m = 0; m < 4; ++m)
#pragma unroll
        for (int n = 0; n < 4; ++n) acc[m][n] = (f32x4){0.f, 0.f, 0.f, 0.f};

    const int frow = lane & 15;
    const int fko  = (((lane >> 4) ^ ((frow >> 1) & 3)) * 8);

    for (int k0 = 0; k0 < D_; k0 += 32) {
        GLD16(Ah + gA0 + k0, &AT[l0]);
        GLD16(Ah + gA1 + k0, &AT[l1]);
        GLD16(Wh + gB0 + k0, &BT[l0]);
        GLD16(Wh + gB1 + k0, &BT[l1]);
        __syncthreads();
        short8 bf[4];
#pragma unroll
        for (int n = 0; n < 4; ++n)
            bf[n] = *(const short8*)&BT[(wc * 64 + n * 16 + frow) * 32 + fko];
#pragma unroll
        for (int m = 0; m < 4; ++m) {
            short8 a = *(const short8*)&AT[(wr * 64 + m * 16 + frow) * 32 + fko];
#pragma unroll
            for (int n = 0; n < 4; ++n)
                acc[m][n] = __builtin_amdgcn_mfma_f32_16x16x32_bf16(a, bf[n], acc[m][n], 0, 0, 0);
        }
        __syncthreads();
    }

    if (z == 0) {
#pragma unroll
        for (int n = 0; n < 4; ++n) {
            int col = bcol + wc * 64 + n * 16 + frow;
            float bsv = bias[col];
#pragma unroll
            for (int m = 0; m < 4; ++m) {
                int rbase = brow + wr * 64 + m * 16 + (lane >> 4) * 4;
#pragma unroll
                for (int r = 0; r < 4; ++r)
                    Kb[(size_t)(rbase + r) * D_ + col] = f2bf(acc[m][n][r] + bsv);
            }
        }
    } else {
#pragma unroll
        for (int n = 0; n < 4; ++n) {
            int col = bcol + wc * 64 + n * 16 + frow;
            int h   = col >> 6, d = col & 63;
            float bsv = bias[col];
#pragma unroll
            for (int m = 0; m < 4; ++m) {
                int rbase = brow + wr * 64 + m * 16 + (lane >> 4) * 4;
                int b     = rbase >> 13;
                int tok   = rbase & (TK_ - 1);
                ushort4 o;
                o.x = f2bf(acc[m][n][0] + bsv);
                o.y = f2bf(acc[m][n][1] + bsv);
                o.z = f2bf(acc[m][n][2] + bsv);
                o.w = f2bf(acc[m][n][3] + bsv);
                *(ushort4*)&Vt[((size_t)(b * 16 + h) * 64 + d) * TK_ + tok] = o;
            }
        }
    }
}

// ---------------- MFMA flash attention, fixed-max (m=0) softmax, setprio on MFMA ----------------
template<bool FULL>
__device__ __forceinline__ void attn_pass(
    const f32x4 st[4], int jb, int lo, int hi,
    f32x4& lacc, f32x4 o[4],
    unsigned short* Ps, const unsigned short* Vs,
    int frow, int g, int w)
{
    const int q = w * 16 + frow;
    const short8 kOnes = {(short)0x3F80, (short)0x3F80, (short)0x3F80, (short)0x3F80,
                          (short)0x3F80, (short)0x3F80, (short)0x3F80, (short)0x3F80};
    float p[4][4];
#pragma unroll
    for (int mt = 0; mt < 4; ++mt)
#pragma unroll
        for (int r = 0; r < 4; ++r) {
            float pv = EXP2F(st[mt][r]);
            if (!FULL) {
                int key = jb + mt * 16 + g * 4 + r;
                if (key < lo || key >= hi) pv = 0.f;
            }
            p[mt][r] = pv;
        }

#pragma unroll
    for (int mt = 0; mt < 4; ++mt) {
        unsigned u0, u1;
        asm("v_cvt_pk_bf16_f32 %0, %1, %2" : "=v"(u0) : "v"(p[mt][0]), "v"(p[mt][1]));
        asm("v_cvt_pk_bf16_f32 %0, %1, %2" : "=v"(u1) : "v"(p[mt][2]), "v"(p[mt][3]));
        unsigned* dst = (unsigned*)((char*)Ps + q * 144 + (mt * 16 + g * 4) * 2);
        dst[0] = u0; dst[1] = u1;
    }
    __builtin_amdgcn_sched_barrier(0);   // keep PV reads after P writes

    short8 pb[2];
#pragma unroll
    for (int ks = 0; ks < 2; ++ks)
        pb[ks] = *(const short8*)((const char*)Ps + q * 144 + ks * 64 + g * 16);
    __builtin_amdgcn_s_setprio(1);
#pragma unroll
    for (int mt = 0; mt < 4; ++mt) {
        int row = mt * 16 + frow;
        int rs  = (row & 7) << 4;
#pragma unroll
        for (int ks = 0; ks < 2; ++ks) {
            short8 a = *(const short8*)((const char*)Vs + row * 128 + ((ks * 64 + g * 16) ^ rs));
            o[mt] = __builtin_amdgcn_mfma_f32_16x16x32_bf16(a, pb[ks], o[mt], 0, 0, 0);
        }
    }
#pragma unroll
    for (int ks = 0; ks < 2; ++ks)
        lacc = __builtin_amdgcn_mfma_f32_16x16x32_bf16(kOnes, pb[ks], lacc, 0, 0, 0);
    __builtin_amdgcn_s_setprio(0);
}

__global__ __launch_bounds__(256)
void sdpca_attn_mfma(const unsigned short* __restrict__ Qb,
                     const unsigned short* __restrict__ Kb,
                     const unsigned short* __restrict__ Vt,
                     const int* __restrict__ nactp,
                     unsigned short* __restrict__ pO, float* __restrict__ pL)
{
    __shared__ char smem[25600];
    unsigned short* Ks = (unsigned short*)smem;
    unsigned short* Vs = (unsigned short*)(smem + 8192);
    unsigned short* Ps = (unsigned short*)(smem + 16384);
    float*          Ot = (float*)smem;

    const int tid  = threadIdx.x;
    const int l    = tid & 63, w = tid >> 6;
    const int frow = l & 15,  g = l >> 4;

    const int bid = blockIdx.x;
    const int lid = (bid & 7) * 256 + (bid >> 3);
    const int q0  = (lid & 7) * 64;
    const int bh  = (lid >> 3) & 31;
    const int s   = lid >> 8;
    const int b   = bh >> 4, h = bh & 15;

    const int Na   = *nactp;
    const int ks0  = s * (TK_ / ASPLIT);
    const int nt   = TK_ / ASPLIT / 64;

    short8 qf0, qf1;
    {
        const unsigned short* qp = Qb + (size_t)(b * TQ_ + q0 + w * 16 + frow) * D_ + h * HD_;
        qf0 = *(const short8*)(qp + g * 8);
        qf1 = *(const short8*)(qp + 32 + g * 8);
    }

    f32x4 lA4 = (f32x4){0.f, 0.f, 0.f, 0.f};
    f32x4 lI4 = (f32x4){0.f, 0.f, 0.f, 0.f};
    f32x4 oA[4], oI[4];
#pragma unroll
    for (int mt = 0; mt < 4; ++mt) {
        oA[mt] = (f32x4){0.f, 0.f, 0.f, 0.f};
        oI[mt] = (f32x4){0.f, 0.f, 0.f, 0.f};
    }

    const int srow = tid >> 2;
    const int scb  = (tid & 3) * 32;
    const unsigned short* kg = Kb + (size_t)(b * TK_ + ks0 + srow) * D_ + h * HD_ + (tid & 3) * 16;
    const unsigned short* vg = Vt + ((size_t)bh * HD_ + srow) * TK_ + ks0 + (tid & 3) * 16;
    const int kswz0 = srow * 128 + ((scb +  0) ^ ((srow & 7) << 4));
    const int kswz1 = srow * 128 + ((scb + 16) ^ ((srow & 7) << 4));

    // prefetch tile 0
    short8 kr0 = *(const short8*)(kg);
    short8 kr1 = *(const short8*)(kg + 8);
    short8 vr0 = *(const short8*)(vg);
    short8 vr1 = *(const short8*)(vg + 8);
    kg += (size_t)64 * D_;
    vg += 64;

    for (int t = 0; t < nt; ++t) {
        const int jb = ks0 + t * 64;
        __syncthreads();
        *(short8*)((char*)Ks + kswz0) = kr0;
        *(short8*)((char*)Ks + kswz1) = kr1;
        *(short8*)((char*)Vs + kswz0) = vr0;
        *(short8*)((char*)Vs + kswz1) = vr1;
        __syncthreads();

        if (t + 1 < nt) {
            kr0 = *(const short8*)(kg);
            kr1 = *(const short8*)(kg + 8);
            vr0 = *(const short8*)(vg);
            vr1 = *(const short8*)(vg + 8);
            kg += (size_t)64 * D_;
            vg += 64;
        }

        f32x4 st[4];
        __builtin_amdgcn_s_setprio(1);
#pragma unroll
        for (int mt = 0; mt < 4; ++mt) {
            int row = mt * 16 + frow;
            int rs  = (row & 7) << 4;
            short8 a0 = *(const short8*)((const char*)Ks + row * 128 + ((g * 16) ^ rs));
            short8 a1 = *(const short8*)((const char*)Ks + row * 128 + ((64 + g * 16) ^ rs));
            f32x4 acc = (f32x4){0.f, 0.f, 0.f, 0.f};
            acc = __builtin_amdgcn_mfma_f32_16x16x32_bf16(a0, qf0, acc, 0, 0, 0);
            acc = __builtin_amdgcn_mfma_f32_16x16x32_bf16(a1, qf1, acc, 0, 0, 0);
            st[mt] = acc;
        }
        __builtin_amdgcn_s_setprio(0);

        const bool hasA = (jb < Na);
        const bool hasI = (jb + 64 > Na);
        if (hasA) {
            if (jb + 64 <= Na) attn_pass<true >(st, jb, 0, Na, lA4, oA, Ps, Vs, frow, g, w);
            else               attn_pass<false>(st, jb, 0, Na, lA4, oA, Ps, Vs, frow, g, w);
        }
        if (hasI) {
            if (jb >= Na)      attn_pass<true >(st, jb, Na, TK_, lI4, oI, Ps, Vs, frow, g, w);
            else               attn_pass<false>(st, jb, Na, TK_, lI4, oI, Ps, Vs, frow, g, w);
        }
    }

    const int q = w * 16 + frow;
#pragma unroll
    for (int grp = 0; grp < 2; ++grp) {
        __syncthreads();
        const f32x4* o = grp ? oI : oA;
#pragma unroll
        for (int mt = 0; mt < 4; ++mt)
            *(f32x4*)&Ot[q * 68 + mt * 16 + g * 4] = o[mt];
        if (g == 0) {
            size_t base = ((size_t)((s * 2 + grp) * (B_ * NH_) + bh)) * TQ_ + q0 + q;
            pL[base] = grp ? lI4[0] : lA4[0];
        }
        __syncthreads();
        {
            int qr = tid >> 2, dc = (tid & 3) * 16;
            size_t rowbase = ((size_t)((s * 2 + grp) * (B_ * NH_) + bh)) * TQ_ + q0 + qr;
            unsigned short* dst = pO + rowbase * HD_ + dc;
            union { short8 v; unsigned short u[8]; } o0, o1;
#pragma unroll
            for (int j = 0; j < 8; ++j) {
                o0.u[j] = f2bf(Ot[qr * 68 + dc + j]);
                o1.u[j] = f2bf(Ot[qr * 68 + dc + 8 + j]);
            }
            *(short8*)(dst)     = o0.v;
            *(short8*)(dst + 8) = o1.v;
        }
    }
}

// ---------------- split-K merge: plain sums (shared m=0), bf16 pO in, bf16 out ----------------
__global__ __launch_bounds__(256)
void sdpca_combine(const unsigned short* __restrict__ pO, const float* __restrict__ pL,
                   const int* __restrict__ nactp, unsigned short* __restrict__ Aob)
{
    int idx = blockIdx.x * 256 + threadIdx.x;
    int d   = idx & (HD_ - 1);
    int q   = (idx >> 6) & (TQ_ - 1);
    int bh  = idx >> 15;
    int b   = bh >> 4, h = bh & 15;
    int Na  = *nactp;
    int Ni  = TK_ - Na;

    float res = 0.f;
#pragma unroll
    for (int gg = 0; gg < 2; ++gg) {
        float L = 0.f, O = 0.f;
#pragma unroll
        for (int ss = 0; ss < ASPLIT; ++ss) {
            size_t ii = ((size_t)((ss * 2 + gg) * (B_ * NH_) + bh)) * TQ_ + q;
            L += pL[ii];
            O += bf2f(pO[ii * HD_ + d]);
        }
        float r   = (L > 0.f) ? (O / L) : 0.f;
        int   cnt = (gg == 0) ? Na : Ni;
        float sc  = (cnt > 0) ? rsqrtf((float)cnt) : 0.f;
        res += (gg == 0) ? (sc * r) : (-sc * r);
    }
    Aob[((size_t)(b * TQ_ + q)) * D_ + h * HD_ + d] = f2bf(res);
}

// ---------------- output projection, bf16 MFMA, fp32 out ----------------
__global__ __launch_bounds__(256)
void sdpca_gemm_o(const unsigned short* __restrict__ A, const unsigned short* __restrict__ W,
                  const float* __restrict__ bias, float* __restrict__ C)
{
    __shared__ unsigned short AT[128 * 32];
    __shared__ unsigned short BT[128 * 32];
    const int tid  = threadIdx.x;
    const int lane = tid & 63;
    const int w    = tid >> 6;
    const int brow = blockIdx.y * 128;
    const int bcol = blockIdx.x * 128;
    const int wr = w >> 1, wc = w & 1;

    const int   srow = lane >> 2;
    const int   scol = (((lane & 3) ^ ((lane >> 3) & 3)) * 8);
    const size_t gA0 = (size_t)(brow + w * 32 + srow) * D_ + scol;
    const size_t gA1 = gA0 + (size_t)16 * D_;
    const size_t gB0 = (size_t)(bcol + w * 32 + srow) * D_ + scol;
    const size_t gB1 = gB0 + (size_t)16 * D_;
    const int   l0   = (w * 32 +  0) * 32;
    const int   l1   = (w * 32 + 16) * 32;

    f32x4 acc[4][4];
#pragma unroll
    for (int m = 0; m < 4; ++m)
#pragma unroll
        for (int n = 0; n < 4; ++n) acc[m][n] = (f32x4){0.f, 0.f, 0.f, 0.f};

    const int frow = lane & 15;
    const int fko  = (((lane >> 4) ^ ((frow >> 1) & 3)) * 8);

    for (int k0 = 0; k0 < D_; k0 += 32) {
        GLD16(A + gA0 + k0, &AT[l0]);
        GLD16(A + gA1 + k0, &AT[l1]);
        GLD16(W + gB0 + k0, &BT[l0]);
        GLD16(W + gB1 + k0, &BT[l1]);
        __syncthreads();
        short8 bf[4];
#pragma unroll
        for (int n = 0; n < 4; ++n)
            bf[n] = *(const short8*)&BT[(wc * 64 + n * 16 + frow) * 32 + fko];
#pragma unroll
        for (int m = 0; m < 4; ++m) {
            short8 a = *(const short8*)&AT[(wr * 64 + m * 16 + frow) * 32 + fko];
#pragma unroll
            for (int n = 0; n < 4; ++n)
                acc[m][n] = __builtin_amdgcn_mfma_f32_16x16x32_bf16(a, bf[n], acc[m][n], 0, 0, 0);
        }
        __syncthreads();
    }

#pragma unroll
    for (int n = 0; n < 4; ++n) {
        int col = bcol + wc * 64 + n * 16 + frow;
        float bsv = bias[col];
#pragma unroll
        for (int m = 0; m < 4; ++m) {
            int rbase = brow + wr * 64 + m * 16 + (lane >> 4) * 4;
#pragma unroll
            for (int r = 0; r < 4; ++r)
                C[(size_t)(rbase + r) * D_ + col] = acc[m][n][r] + bsv;
        }
    }
}

extern "C" void kernel_launch(void* const* d_in, const int* in_sizes, int n_in,
                              void* d_out, int out_size, void* d_ws, size_t ws_size,
                              hipStream_t stream) {
    (void)in_sizes; (void)n_in; (void)out_size; (void)ws_size;
    const float* q   = (const float*)d_in[0];
    const float* kv  = (const float*)d_in[1];
    const float* Wq  = (const float*)d_in[2];
    const float* bq  = (const float*)d_in[3];
    const float* Wk  = (const float*)d_in[4];
    const float* bk  = (const float*)d_in[5];
    const float* Wv  = (const float*)d_in[6];
    const float* bv  = (const float*)d_in[7];
    const float* Wo  = (const float*)d_in[8];
    const float* bo  = (const float*)d_in[9];
    const float* ab  = (const float*)d_in[10];
    const float* ib  = (const float*)d_in[11];
    const float* lt  = (const float*)d_in[12];
    const int*   na  = (const int*)d_in[13];

    char* ws = (char*)d_ws;
    const size_t nQ  = (size_t)B_ * TQ_ * D_;    // 1,048,576
    const size_t nKV = (size_t)B_ * TK_ * D_;    // 16,777,216
    const size_t nW  = (size_t)D_ * D_;          // 1,048,576 (== nQ)
    const size_t nML = (size_t)ASPLIT * 2 * B_ * NH_ * TQ_;  // 262,144

    unsigned short* Ah  = (unsigned short*)ws;                 // 33.5 MB
    unsigned short* Whk = Ah + nKV;                            // 2 MB
    unsigned short* Whv = Whk + nW;                            // 2 MB
    unsigned short* Kb  = Whv + nW;                            // 33.5 MB
    unsigned short* Vt  = Kb + nKV;                            // 33.5 MB
    unsigned short* Qb  = Vt + nKV;                            // 2 MB
    unsigned short* qbb = Qb + nQ;                             // 2 MB
    unsigned short* Wqb = qbb + nQ;                            // 2 MB
    unsigned short* Wob = Wqb + nW;                            // 2 MB
    unsigned short* Aob = Wob + nW;                            // 2 MB
    float* pL = (float*)(Aob + nQ);                            // 1 MB
    unsigned short* pO = (unsigned short*)(pL + nML);          // 33.5 MB
    // total ~147 MB

    dim3 blk(256);
    split_w5          <<<dim3((int)(nW / 8 / 256), 5), blk, 0, stream>>>(
        q, Wq, Wo, Wk, Wv, qbb, Wqb, Wob, Whk, Whv);
    split_kv          <<<dim3((int)(nKV / 8 / 256)), blk, 0, stream>>>(kv, ab, ib, na, Ah);
    sdpca_gemm_q      <<<dim3(8, 8),                 blk, 0, stream>>>(qbb, Wqb, bq, lt, Qb);
    sdpca_gemm_kv_mfma<<<dim3(1024, 2),              blk, 0, stream>>>(Ah, Whk, Whv, bk, bv, Kb, Vt);
    sdpca_attn_mfma   <<<dim3(2048),                 blk, 0, stream>>>(Qb, Kb, Vt, na, pO, pL);
    sdpca_combine     <<<dim3((B_ * TQ_ * D_) / 256), blk, 0, stream>>>(pO, pL, na, Aob);
    sdpca_gemm_o      <<<dim3(8, 8),                 blk, 0, stream>>>(Aob, Wob, bo, (float*)d_out);
}